// Round 2
// baseline (5561.118 us; speedup 1.0000x reference)
//
#include <hip/hip_runtime.h>

#define B_ 64
#define S_ 128
#define H_ 512
#define NBLK 256        // 4 batch-tiles x 64 i-groups (8 h-idx each)
#define HW_TARGET 256   // arrivals per (btile, step): 4 h-waves x 64 blocks
#define GUARD_MAX (1 << 17)

// ---------------------------------------------------------------------------
// gru_seq: persistent, 256 blocks x 512 thr, LDS exactly 80KB -> 2 blocks/CU
//   capacity (co-residency robust for >=128 usable CUs).
//   block g: btile bt=g>>6 (16 batches), i-group i0=(g&63)*8.
//   waves 0-3 (h-role): h-side matvec from LDS whh + gates; h(s) stored into
//     out[b][s][0:512] via relaxed AGENT atomics (sc1, Infinity-Cache
//     coherent -> no fences, no L2 invalidation, weights stay cached).
//     Arrival: s_waitcnt vmcnt(0) then agent atomicAdd on bar[bt][s];
//     waiters spin on relaxed agent loads (no cache maintenance needed since
//     h is re-read via agent atomic loads too).
//   waves 4-7 (x-role): x-side matvec for step s+1 (emb gather + W_ih from
//     L1/L2), result handed off through the context half of out rows
//     2*g / 2*g+1 (dead until attn overwrites) via agent atomics.
// attn_out: 8192 fully-parallel blocks; h already in out, writes context only.
// Workspace: bar[4][128] int = 2KB, zeroed via hipMemsetAsync each launch.
// ---------------------------------------------------------------------------

// float4-granular LDS swizzles (per-quarter-wave conflict-free; see notes)
__device__ __forceinline__ int swzW(int k4) { return k4 ^ ((k4 >> 4) & 7); }
__device__ __forceinline__ int swzH(int r, int k4) { return k4 ^ ((r >> 1) & 7); }

__global__ __launch_bounds__(512, 4) void gru_seq(
    const int*   __restrict__ dec,   // [64][128]
    const float* __restrict__ eh,    // [64][512]
    const float* __restrict__ emb,   // [32000][512]
    const float* __restrict__ wih,   // [1536][512]
    const float* __restrict__ whh,   // [1536][512]
    const float* __restrict__ bih,   // [1536]
    const float* __restrict__ bhh,   // [1536]
    float* __restrict__ out,         // [64][128][1024]
    int*   __restrict__ bar)         // [4][128]
{
  __shared__ __align__(16) float whh_s[24 * 512];  // 48 KB
  __shared__ __align__(16) float h_s[16 * 512];    // 32 KB   (total = 80 KB)

  const int tid  = threadIdx.x;
  const int wave = tid >> 6;
  const int lane = tid & 63;
  const int bp   = lane & 7;       // batch pair 0..7
  const int q    = lane >> 3;      // k-chunk 0..7 (64 floats each)
  const int bt   = blockIdx.x >> 6;
  const int i0   = (blockIdx.x & 63) * 8;
  const int b0g  = bt * 16;
  const bool hrole = (wave < 4);
  const int ilA  = (hrole ? wave : (wave - 4)) * 2;
  const int bsel = (q >> 1) & 1, ilsel = q & 1;
  const int my_b  = 2 * bp + bsel;
  const int my_il = ilA + ilsel;
  const int my_i  = i0 + my_il;

  float4* whh4 = (float4*)whh_s;
  float4* h4   = (float4*)h_s;

  // ---- stage whh slice (24 rows) into LDS once ----
  {
    const int f4 = tid & 127, r0 = tid >> 7;
    #pragma unroll
    for (int m = 0; m < 6; ++m) {
      const int row = r0 + 4 * m;              // 0..23 = gate*8 + il
      const int g = row >> 3, il = row & 7;
      whh4[row * 128 + swzW(f4)] =
          ((const float4*)whh)[(size_t)(g * 512 + i0 + il) * 128 + f4];
    }
  }

  float b_ir = 0, b_iz = 0, b_in = 0, b_hr = 0, b_hz = 0, b_hn = 0;
  if (hrole && q < 4) {
    b_ir = bih[my_i]; b_iz = bih[512 + my_i]; b_in = bih[1024 + my_i];
    b_hr = bhh[my_i]; b_hz = bhh[512 + my_i]; b_hn = bhh[1024 + my_i];
  }

  // ---- x-side matvec for step ts -> xg scratch row (agent atomics) ----
  auto xside = [&](int ts) {
    const int tok0 = dec[(b0g + 2 * bp)     * S_ + ts];
    const int tok1 = dec[(b0g + 2 * bp + 1) * S_ + ts];
    const float4* x0 = (const float4*)(emb + (size_t)tok0 * H_);
    const float4* x1 = (const float4*)(emb + (size_t)tok1 * H_);
    const int kq = q * 16;
    const float4* w4 = (const float4*)wih;
    const float4* wp[3][2];
    #pragma unroll
    for (int g = 0; g < 3; ++g)
      #pragma unroll
      for (int e = 0; e < 2; ++e)
        wp[g][e] = w4 + (size_t)(g * 512 + i0 + ilA + e) * 128 + kq;
    float a[2][2][3] = {};
    #pragma unroll 4
    for (int c = 0; c < 16; ++c) {
      const float4 xv0 = x0[kq + c];
      const float4 xv1 = x1[kq + c];
      #pragma unroll
      for (int g = 0; g < 3; ++g) {
        #pragma unroll
        for (int e = 0; e < 2; ++e) {
          const float4 wv = wp[g][e][c];
          a[0][e][g] = fmaf(xv0.x, wv.x, fmaf(xv0.y, wv.y,
                       fmaf(xv0.z, wv.z, fmaf(xv0.w, wv.w, a[0][e][g]))));
          a[1][e][g] = fmaf(xv1.x, wv.x, fmaf(xv1.y, wv.y,
                       fmaf(xv1.z, wv.z, fmaf(xv1.w, wv.w, a[1][e][g]))));
        }
      }
    }
    #pragma unroll
    for (int bb = 0; bb < 2; ++bb)
      #pragma unroll
      for (int e = 0; e < 2; ++e)
        #pragma unroll
        for (int g = 0; g < 3; ++g) {
          float v = a[bb][e][g];
          v += __shfl_xor(v, 8); v += __shfl_xor(v, 16); v += __shfl_xor(v, 32);
          a[bb][e][g] = v;
        }
    if (q < 4) {
      float* xq = out + (size_t)(2 * blockIdx.x + (ts & 1)) * 1024 + 512;
      const int xi = (my_b * 8 + my_il) * 3;
      #pragma unroll
      for (int g = 0; g < 3; ++g)
        __hip_atomic_store(xq + xi + g, a[bsel][ilsel][g],
                           __ATOMIC_RELAXED, __HIP_MEMORY_SCOPE_AGENT);
    }
  };

  // ---- stage h(s) tile from out (agent atomic u64 loads) into LDS ----
  auto stage_hg = [&](int sh) {
    const int r = tid >> 4, c0 = tid & 15;    // h-wave tids 0..255
    const unsigned long long* src = (const unsigned long long*)
        (out + ((size_t)(b0g + r) * S_ + sh) * 1024);
    #pragma unroll
    for (int j = 0; j < 8; ++j) {
      const int k4 = c0 + 16 * j;
      const unsigned long long lo = __hip_atomic_load(
          src + 2 * k4, __ATOMIC_RELAXED, __HIP_MEMORY_SCOPE_AGENT);
      const unsigned long long hi = __hip_atomic_load(
          src + 2 * k4 + 1, __ATOMIC_RELAXED, __HIP_MEMORY_SCOPE_AGENT);
      float4 v;
      v.x = __uint_as_float((unsigned)lo); v.y = __uint_as_float((unsigned)(lo >> 32));
      v.z = __uint_as_float((unsigned)hi); v.w = __uint_as_float((unsigned)(hi >> 32));
      h4[r * 128 + swzH(r, k4)] = v;
    }
  };

  // ---- prelude: h(-1)=eh into LDS (normal loads); xg(0) ----
  if (hrole) {
    const int r = tid >> 4, c0 = tid & 15;
    const float4* src = (const float4*)(eh + (size_t)(b0g + r) * H_);
    #pragma unroll
    for (int j = 0; j < 8; ++j) {
      const int k4 = c0 + 16 * j;
      h4[r * 128 + swzH(r, k4)] = src[k4];
    }
  } else {
    xside(0);
  }
  __syncthreads();

  // ---- recurrence ----
  for (int s = 0; s < S_; ++s) {
    if (hrole) {
      // h-side matvec from LDS
      const int kq = q * 16;
      const int br0 = 2 * bp, br1 = br0 + 1;
      float a[2][2][3] = {};
      #pragma unroll 4
      for (int c = 0; c < 16; ++c) {
        const int k4 = kq + c;
        const float4 hv0 = h4[br0 * 128 + swzH(br0, k4)];
        const float4 hv1 = h4[br1 * 128 + swzH(br1, k4)];
        const int ws = swzW(k4);
        #pragma unroll
        for (int g = 0; g < 3; ++g) {
          #pragma unroll
          for (int e = 0; e < 2; ++e) {
            const float4 wv = whh4[(g * 8 + ilA + e) * 128 + ws];
            a[0][e][g] = fmaf(hv0.x, wv.x, fmaf(hv0.y, wv.y,
                         fmaf(hv0.z, wv.z, fmaf(hv0.w, wv.w, a[0][e][g]))));
            a[1][e][g] = fmaf(hv1.x, wv.x, fmaf(hv1.y, wv.y,
                         fmaf(hv1.z, wv.z, fmaf(hv1.w, wv.w, a[1][e][g]))));
          }
        }
      }
      #pragma unroll
      for (int bb = 0; bb < 2; ++bb)
        #pragma unroll
        for (int e = 0; e < 2; ++e)
          #pragma unroll
          for (int g = 0; g < 3; ++g) {
            float v = a[bb][e][g];
            v += __shfl_xor(v, 8); v += __shfl_xor(v, 16); v += __shfl_xor(v, 32);
            a[bb][e][g] = v;
          }
      if (q < 4) {
        const float* xq = out + (size_t)(2 * blockIdx.x + (s & 1)) * 1024 + 512;
        const int xi = (my_b * 8 + my_il) * 3;
        const float xr = __hip_atomic_load(xq + xi + 0, __ATOMIC_RELAXED, __HIP_MEMORY_SCOPE_AGENT);
        const float xz = __hip_atomic_load(xq + xi + 1, __ATOMIC_RELAXED, __HIP_MEMORY_SCOPE_AGENT);
        const float xn = __hip_atomic_load(xq + xi + 2, __ATOMIC_RELAXED, __HIP_MEMORY_SCOPE_AGENT);
        const float ir  = xr + b_ir;
        const float iz  = xz + b_iz;
        const float in2 = xn + b_in;
        const float hr = a[bsel][ilsel][0] + b_hr;
        const float hz = a[bsel][ilsel][1] + b_hz;
        const float hn = a[bsel][ilsel][2] + b_hn;
        const float rr = 1.f / (1.f + expf(-(ir + hr)));
        const float zz = 1.f / (1.f + expf(-(iz + hz)));
        const float nn = tanhf(in2 + rr * hn);
        const int k4o = my_i >> 2;
        const float hold = h_s[my_b * 512 + (swzH(my_b, k4o) << 2) + (my_i & 3)];
        const float hnew = (1.f - zz) * nn + zz * hold;
        __hip_atomic_store(out + ((size_t)(b0g + my_b) * S_ + s) * 1024 + my_i,
                           hnew, __ATOMIC_RELAXED, __HIP_MEMORY_SCOPE_AGENT);
      }
      if (s < S_ - 1) {
        asm volatile("s_waitcnt vmcnt(0)" ::: "memory");  // drain h stores (sc1 -> coherent point)
        if (lane == 0)
          __hip_atomic_fetch_add(bar + bt * S_ + s, 1,
                                 __ATOMIC_RELAXED, __HIP_MEMORY_SCOPE_AGENT);
      }
    } else if (s < S_ - 1) {
      xside(s + 1);   // overlaps h critical path; no spin needed
    }

    if (s + 1 < S_) {
      if (hrole) {
        const int* flag = bar + bt * S_ + s;
        int g2 = 0;
        while (__hip_atomic_load(flag, __ATOMIC_RELAXED, __HIP_MEMORY_SCOPE_AGENT)
                   < HW_TARGET && ++g2 < GUARD_MAX) {}
        asm volatile("" ::: "memory");
        stage_hg(s);
      }
      __syncthreads();   // h_s staged; xg(s+1) drained (vmcnt 0 at barrier)
    }
  }
}

// ---------------------------------------------------------------------------
__global__ __launch_bounds__(256) void attn_out(
    const float* __restrict__ enc,   // [64][128][512]
    float* __restrict__ out)         // [64][128][1024]; h-half already filled
{
  __shared__ __align__(16) float hsm[H_];
  __shared__ float pp[S_];
  __shared__ float red[4];
  const int tid = threadIdx.x;
  const int bid = blockIdx.x;
  const int b = bid & 63;            // b -> XCD b%8 (enc[b] L2-resident)
  const int s = bid >> 6;

  const float* hsrc = out + ((size_t)b * S_ + s) * 1024;
  *(float2*)(hsm + tid * 2) = *(const float2*)(hsrc + tid * 2);
  __syncthreads();

  const int sr = tid >> 1, hf = tid & 1;
  float sc = 0.f;
  {
    const float* erow = enc + ((size_t)b * S_ + sr) * H_ + hf * 256;
    const float* hp = hsm + hf * 256;
    #pragma unroll 8
    for (int c = 0; c < 64; ++c) {
      const float4 ev = ((const float4*)erow)[c];
      const float4 hv = ((const float4*)hp)[c];
      sc = fmaf(ev.x, hv.x, sc); sc = fmaf(ev.y, hv.y, sc);
      sc = fmaf(ev.z, hv.z, sc); sc = fmaf(ev.w, hv.w, sc);
    }
  }
  sc += __shfl_xor(sc, 1);
  if (hf == 0) pp[sr] = sc;
  __syncthreads();

  float e = 0.f, v = 0.f;
  if (tid < 128) {
    v = pp[tid];
    float m = v;
    #pragma unroll
    for (int o = 32; o > 0; o >>= 1) m = fmaxf(m, __shfl_xor(m, o));
    if ((tid & 63) == 0) red[tid >> 6] = m;
  }
  __syncthreads();
  const float mx = fmaxf(red[0], red[1]);
  if (tid < 128) {
    e = expf(v - mx);
    float s2 = e;
    #pragma unroll
    for (int o = 32; o > 0; o >>= 1) s2 += __shfl_xor(s2, o);
    if ((tid & 63) == 0) red[2 + (tid >> 6)] = s2;
  }
  __syncthreads();
  const float inv = 1.f / (red[2] + red[3]);
  if (tid < 128) pp[tid] = e * inv;
  __syncthreads();

  const int i2 = tid * 2;
  float c0 = 0.f, c1 = 0.f;
  const float* ecol = enc + (size_t)b * (S_ * H_) + i2;
  for (int s2 = 0; s2 < S_; ++s2) {
    const float2 u = *(const float2*)(ecol + (size_t)s2 * H_);
    const float p = pp[s2];
    c0 = fmaf(p, u.x, c0); c1 = fmaf(p, u.y, c1);
  }
  const size_t base = ((size_t)b * S_ + s) * (2 * H_);
  *(float2*)(out + base + H_ + i2) = make_float2(c0, c1);  // context half only
}

// ---------------------------------------------------------------------------
extern "C" void kernel_launch(void* const* d_in, const int* in_sizes, int n_in,
                              void* d_out, int out_size, void* d_ws, size_t ws_size,
                              hipStream_t stream) {
  (void)in_sizes; (void)n_in; (void)out_size; (void)ws_size;
  const int*   dec = (const int*)d_in[0];
  const float* eh  = (const float*)d_in[1];
  const float* enc = (const float*)d_in[2];
  const float* emb = (const float*)d_in[3];
  const float* wih = (const float*)d_in[4];
  const float* whh = (const float*)d_in[5];
  const float* bih = (const float*)d_in[6];
  const float* bhh = (const float*)d_in[7];
  float* out = (float*)d_out;
  int*   bar = (int*)d_ws;                                   // 2 KB only

  hipMemsetAsync(bar, 0, 4 * S_ * sizeof(int), stream);      // clean flags
  gru_seq<<<NBLK, 512, 0, stream>>>(dec, eh, emb, wih, whh, bih, bhh, out, bar);
  attn_out<<<B_ * S_, 256, 0, stream>>>(enc, out);
}

// Round 3
// 1774.469 us; speedup vs baseline: 3.1340x; 3.1340x over previous
//
#include <hip/hip_runtime.h>

typedef float f32x4 __attribute__((ext_vector_type(4)));

#define B_ 64
#define S_ 128
#define H_ 512
#define NBLK 256        // 4 batch-tiles x 64 i-groups (8 h-idx each)
#define BT_TARGET 64    // one arrival per block per (btile, step)
#define GUARD_MAX (1 << 16)

// ---------------------------------------------------------------------------
// gru_seq: persistent, 256 blocks x 512 thr, 134 KB LDS -> 1 block/CU, all
//   256 blocks co-resident (proven in round 2 by correctness of the sync).
//   block g: btile bt=g>>6 (16 batches), i-group i0=(g&63)*8.
//   waves 0-3 (h-role): h-side matvec from LDS whh + gates; h(s) published to
//     out[b][s][0:512] via relaxed AGENT atomic stores (write-through to IF).
//   waves 4-7 (x-role): x-side matvec for step s+1 (emb gather + LDS wih),
//     result handed off via LDS xres (block-local — round-2's global-atomic
//     handoff was pure overhead).
//   Per step: {compute || xside} -> barrier A (drains stores) -> tid0
//     atomicAdd(flag) -> h-waves spin (relaxed agent load) -> stage h via
//     COALESCED inline-asm global_load_dwordx4 sc0 sc1 (bypasses stale
//     L1/L2, reads IF with full line coalescing — replaces round-2's 4096
//     atomic point-ops per block per step, the 40 us/step killer) -> B.
// attn_out: 8192 fully-parallel blocks; h already in out, writes context only.
// Workspace: bar[4][128] int = 2 KB, zeroed via hipMemsetAsync each launch.
// ---------------------------------------------------------------------------

__device__ __forceinline__ int swzW(int k4) { return k4 ^ ((k4 >> 4) & 7); }
__device__ __forceinline__ int swzH(int r, int k4) { return k4 ^ ((r >> 1) & 7); }

__global__ __launch_bounds__(512, 2) void gru_seq(
    const int*   __restrict__ dec,   // [64][128]
    const float* __restrict__ eh,    // [64][512]
    const float* __restrict__ emb,   // [32000][512]
    const float* __restrict__ wih,   // [1536][512]
    const float* __restrict__ whh,   // [1536][512]
    const float* __restrict__ bih,   // [1536]
    const float* __restrict__ bhh,   // [1536]
    float* __restrict__ out,         // [64][128][1024]
    int*   __restrict__ bar)         // [4][128]
{
  __shared__ __align__(16) float wih_s[24 * 512];  // 48 KB
  __shared__ __align__(16) float whh_s[24 * 512];  // 48 KB
  __shared__ __align__(16) float h_s[16 * 512];    // 32 KB
  __shared__ float xres[2][16][8][3];              // 3 KB (block-local x-gates)

  const int tid  = threadIdx.x;
  const int wave = tid >> 6;
  const int lane = tid & 63;
  const int bp   = lane & 7;       // batch pair 0..7
  const int q    = lane >> 3;      // k-chunk 0..7 (64 floats each)
  const int bt   = blockIdx.x >> 6;
  const int i0   = (blockIdx.x & 63) * 8;
  const int b0g  = bt * 16;
  const bool hrole = (wave < 4);
  const int ilA  = (hrole ? wave : (wave - 4)) * 2;
  const int bsel = (q >> 1) & 1, ilsel = q & 1;
  const int my_b  = 2 * bp + bsel;
  const int my_il = ilA + ilsel;
  const int my_i  = i0 + my_il;

  float4* wih4 = (float4*)wih_s;
  float4* whh4 = (float4*)whh_s;
  float4* h4   = (float4*)h_s;

  // ---- stage both weight slices (24+24 rows) into LDS once ----
  {
    const int f4 = tid & 127, r0 = tid >> 7;
    #pragma unroll
    for (int m = 0; m < 6; ++m) {
      const int row = r0 + 4 * m;              // 0..23 = gate*8 + il
      const int g = row >> 3, il = row & 7;
      const size_t grow = (size_t)(g * 512 + i0 + il) * 128;
      wih4[row * 128 + swzW(f4)] = ((const float4*)wih)[grow + f4];
      whh4[row * 128 + swzW(f4)] = ((const float4*)whh)[grow + f4];
    }
  }

  float b_ir = 0, b_iz = 0, b_in = 0, b_hr = 0, b_hz = 0, b_hn = 0;
  if (hrole && q < 4) {
    b_ir = bih[my_i]; b_iz = bih[512 + my_i]; b_in = bih[1024 + my_i];
    b_hr = bhh[my_i]; b_hz = bhh[512 + my_i]; b_hn = bhh[1024 + my_i];
  }

  // ---- x-side matvec for step ts -> xres[ts&1] (LDS) ----
  auto xside = [&](int ts) {
    const int tok0 = dec[(b0g + 2 * bp)     * S_ + ts];
    const int tok1 = dec[(b0g + 2 * bp + 1) * S_ + ts];
    const float4* x0 = (const float4*)(emb + (size_t)tok0 * H_);
    const float4* x1 = (const float4*)(emb + (size_t)tok1 * H_);
    const int kq = q * 16;
    float a[2][2][3] = {};
    #pragma unroll 4
    for (int c = 0; c < 16; ++c) {
      const int k4 = kq + c;
      const float4 xv0 = x0[k4];
      const float4 xv1 = x1[k4];
      const int ws = swzW(k4);
      #pragma unroll
      for (int g = 0; g < 3; ++g) {
        #pragma unroll
        for (int e = 0; e < 2; ++e) {
          const float4 wv = wih4[(g * 8 + ilA + e) * 128 + ws];
          a[0][e][g] = fmaf(xv0.x, wv.x, fmaf(xv0.y, wv.y,
                       fmaf(xv0.z, wv.z, fmaf(xv0.w, wv.w, a[0][e][g]))));
          a[1][e][g] = fmaf(xv1.x, wv.x, fmaf(xv1.y, wv.y,
                       fmaf(xv1.z, wv.z, fmaf(xv1.w, wv.w, a[1][e][g]))));
        }
      }
    }
    #pragma unroll
    for (int bb = 0; bb < 2; ++bb)
      #pragma unroll
      for (int e = 0; e < 2; ++e)
        #pragma unroll
        for (int g = 0; g < 3; ++g) {
          float v = a[bb][e][g];
          v += __shfl_xor(v, 8); v += __shfl_xor(v, 16); v += __shfl_xor(v, 32);
          a[bb][e][g] = v;
        }
    if (q < 4) {
      const int buf = ts & 1;
      #pragma unroll
      for (int g = 0; g < 3; ++g)
        xres[buf][my_b][my_il][g] = a[bsel][ilsel][g];
    }
  };

  // ---- stage h(s) from out via coalesced agent-coherent loads -> LDS ----
  auto stage_hg = [&](int sh) {
    const int r = tid >> 4, c0 = tid & 15;    // h-wave tids 0..255
    const float* base = out + ((size_t)(b0g + r) * S_ + sh) * 1024 + c0 * 4;
    f32x4 t0, t1, t2, t3, t4, t5, t6, t7;
    asm volatile(
        "global_load_dwordx4 %0, %8, off sc0 sc1\n\t"
        "global_load_dwordx4 %1, %8, off offset:256 sc0 sc1\n\t"
        "global_load_dwordx4 %2, %8, off offset:512 sc0 sc1\n\t"
        "global_load_dwordx4 %3, %8, off offset:768 sc0 sc1\n\t"
        "global_load_dwordx4 %4, %8, off offset:1024 sc0 sc1\n\t"
        "global_load_dwordx4 %5, %8, off offset:1280 sc0 sc1\n\t"
        "global_load_dwordx4 %6, %8, off offset:1536 sc0 sc1\n\t"
        "global_load_dwordx4 %7, %8, off offset:1792 sc0 sc1\n\t"
        "s_waitcnt vmcnt(0)"
        : "=&v"(t0), "=&v"(t1), "=&v"(t2), "=&v"(t3),
          "=&v"(t4), "=&v"(t5), "=&v"(t6), "=&v"(t7)
        : "v"(base) : "memory");
    f32x4* hx = (f32x4*)h_s;
    hx[r * 128 + swzH(r, c0)]       = t0;
    hx[r * 128 + swzH(r, c0 + 16)]  = t1;
    hx[r * 128 + swzH(r, c0 + 32)]  = t2;
    hx[r * 128 + swzH(r, c0 + 48)]  = t3;
    hx[r * 128 + swzH(r, c0 + 64)]  = t4;
    hx[r * 128 + swzH(r, c0 + 80)]  = t5;
    hx[r * 128 + swzH(r, c0 + 96)]  = t6;
    hx[r * 128 + swzH(r, c0 + 112)] = t7;
  };

  __syncthreads();   // weights staged (xside(0) reads wih_s)

  // ---- prelude: h(-1)=eh into LDS; xres[0] ----
  if (hrole) {
    const int r = tid >> 4, c0 = tid & 15;
    const float4* src = (const float4*)(eh + (size_t)(b0g + r) * H_);
    #pragma unroll
    for (int j = 0; j < 8; ++j) {
      const int k4 = c0 + 16 * j;
      h4[r * 128 + swzH(r, k4)] = src[k4];
    }
  } else {
    xside(0);
  }
  __syncthreads();

  // ---- recurrence ----
  for (int s = 0; s < S_; ++s) {
    if (hrole) {
      const int kq = q * 16;
      const int br0 = 2 * bp, br1 = br0 + 1;
      float a[2][2][3] = {};
      #pragma unroll 4
      for (int c = 0; c < 16; ++c) {
        const int k4 = kq + c;
        const float4 hv0 = h4[br0 * 128 + swzH(br0, k4)];
        const float4 hv1 = h4[br1 * 128 + swzH(br1, k4)];
        const int ws = swzW(k4);
        #pragma unroll
        for (int g = 0; g < 3; ++g) {
          #pragma unroll
          for (int e = 0; e < 2; ++e) {
            const float4 wv = whh4[(g * 8 + ilA + e) * 128 + ws];
            a[0][e][g] = fmaf(hv0.x, wv.x, fmaf(hv0.y, wv.y,
                         fmaf(hv0.z, wv.z, fmaf(hv0.w, wv.w, a[0][e][g]))));
            a[1][e][g] = fmaf(hv1.x, wv.x, fmaf(hv1.y, wv.y,
                         fmaf(hv1.z, wv.z, fmaf(hv1.w, wv.w, a[1][e][g]))));
          }
        }
      }
      #pragma unroll
      for (int bb = 0; bb < 2; ++bb)
        #pragma unroll
        for (int e = 0; e < 2; ++e)
          #pragma unroll
          for (int g = 0; g < 3; ++g) {
            float v = a[bb][e][g];
            v += __shfl_xor(v, 8); v += __shfl_xor(v, 16); v += __shfl_xor(v, 32);
            a[bb][e][g] = v;
          }
      if (q < 4) {
        const int buf = s & 1;
        const float ir  = xres[buf][my_b][my_il][0] + b_ir;
        const float iz  = xres[buf][my_b][my_il][1] + b_iz;
        const float in2 = xres[buf][my_b][my_il][2] + b_in;
        const float hr = a[bsel][ilsel][0] + b_hr;
        const float hz = a[bsel][ilsel][1] + b_hz;
        const float hn = a[bsel][ilsel][2] + b_hn;
        const float rr = 1.f / (1.f + expf(-(ir + hr)));
        const float zz = 1.f / (1.f + expf(-(iz + hz)));
        const float nn = tanhf(in2 + rr * hn);
        const int k4o = my_i >> 2;
        const float hold = h_s[my_b * 512 + (swzH(my_b, k4o) << 2) + (my_i & 3)];
        const float hnew = (1.f - zz) * nn + zz * hold;
        __hip_atomic_store(out + ((size_t)(b0g + my_b) * S_ + s) * 1024 + my_i,
                           hnew, __ATOMIC_RELAXED, __HIP_MEMORY_SCOPE_AGENT);
      }
    } else if (s + 1 < S_) {
      xside(s + 1);   // overlaps h critical path
    }

    __syncthreads();  // A: implicit vmcnt(0)/lgkmcnt(0) per wave -> h published

    if (s + 1 < S_) {
      if (tid == 0)
        __hip_atomic_fetch_add(bar + bt * S_ + s, 1,
                               __ATOMIC_RELAXED, __HIP_MEMORY_SCOPE_AGENT);
      if (hrole) {
        const int* flag = bar + bt * S_ + s;
        int g2 = 0;
        while (__hip_atomic_load(flag, __ATOMIC_RELAXED, __HIP_MEMORY_SCOPE_AGENT)
                   < BT_TARGET && ++g2 < GUARD_MAX) {}
        asm volatile("" ::: "memory");
        stage_hg(s);
      }
      __syncthreads();  // B: h_s holds h(s); xres[(s+1)&1] ready
    }
  }
}

// ---------------------------------------------------------------------------
__global__ __launch_bounds__(256) void attn_out(
    const float* __restrict__ enc,   // [64][128][512]
    float* __restrict__ out)         // [64][128][1024]; h-half already filled
{
  __shared__ __align__(16) float hsm[H_];
  __shared__ float pp[S_];
  __shared__ float red[4];
  const int tid = threadIdx.x;
  const int bid = blockIdx.x;
  const int b = bid & 63;            // b -> XCD b%8 (enc[b] L2-resident)
  const int s = bid >> 6;

  const float* hsrc = out + ((size_t)b * S_ + s) * 1024;
  *(float2*)(hsm + tid * 2) = *(const float2*)(hsrc + tid * 2);
  __syncthreads();

  const int sr = tid >> 1, hf = tid & 1;
  float sc = 0.f;
  {
    const float* erow = enc + ((size_t)b * S_ + sr) * H_ + hf * 256;
    const float* hp = hsm + hf * 256;
    #pragma unroll 8
    for (int c = 0; c < 64; ++c) {
      const float4 ev = ((const float4*)erow)[c];
      const float4 hv = ((const float4*)hp)[c];
      sc = fmaf(ev.x, hv.x, sc); sc = fmaf(ev.y, hv.y, sc);
      sc = fmaf(ev.z, hv.z, sc); sc = fmaf(ev.w, hv.w, sc);
    }
  }
  sc += __shfl_xor(sc, 1);
  if (hf == 0) pp[sr] = sc;
  __syncthreads();

  float e = 0.f, v = 0.f;
  if (tid < 128) {
    v = pp[tid];
    float m = v;
    #pragma unroll
    for (int o = 32; o > 0; o >>= 1) m = fmaxf(m, __shfl_xor(m, o));
    if ((tid & 63) == 0) red[tid >> 6] = m;
  }
  __syncthreads();
  const float mx = fmaxf(red[0], red[1]);
  if (tid < 128) {
    e = expf(v - mx);
    float s2 = e;
    #pragma unroll
    for (int o = 32; o > 0; o >>= 1) s2 += __shfl_xor(s2, o);
    if ((tid & 63) == 0) red[2 + (tid >> 6)] = s2;
  }
  __syncthreads();
  const float inv = 1.f / (red[2] + red[3]);
  if (tid < 128) pp[tid] = e * inv;
  __syncthreads();

  const int i2 = tid * 2;
  float c0 = 0.f, c1 = 0.f;
  const float* ecol = enc + (size_t)b * (S_ * H_) + i2;
  for (int s2 = 0; s2 < S_; ++s2) {
    const float2 u = *(const float2*)(ecol + (size_t)s2 * H_);
    const float p = pp[s2];
    c0 = fmaf(p, u.x, c0); c1 = fmaf(p, u.y, c1);
  }
  const size_t base = ((size_t)b * S_ + s) * (2 * H_);
  *(float2*)(out + base + H_ + i2) = make_float2(c0, c1);  // context half only
}

// ---------------------------------------------------------------------------
extern "C" void kernel_launch(void* const* d_in, const int* in_sizes, int n_in,
                              void* d_out, int out_size, void* d_ws, size_t ws_size,
                              hipStream_t stream) {
  (void)in_sizes; (void)n_in; (void)out_size; (void)ws_size;
  const int*   dec = (const int*)d_in[0];
  const float* eh  = (const float*)d_in[1];
  const float* enc = (const float*)d_in[2];
  const float* emb = (const float*)d_in[3];
  const float* wih = (const float*)d_in[4];
  const float* whh = (const float*)d_in[5];
  const float* bih = (const float*)d_in[6];
  const float* bhh = (const float*)d_in[7];
  float* out = (float*)d_out;
  int*   bar = (int*)d_ws;                                   // 2 KB only

  hipMemsetAsync(bar, 0, 4 * S_ * sizeof(int), stream);      // clean flags
  gru_seq<<<NBLK, 512, 0, stream>>>(dec, eh, emb, wih, whh, bih, bhh, out, bar);
  attn_out<<<B_ * S_, 256, 0, stream>>>(enc, out);
}